// Round 7
// baseline (9.904 us; speedup 1.0000x reference)
//
#include <hip/hip_runtime.h>
#include <math.h>

#define TPB 256

__device__ __forceinline__ float frcp(float x) {
#if __has_builtin(__builtin_amdgcn_rcpf)
    return __builtin_amdgcn_rcpf(x);
#else
    return 1.0f / x;
#endif
}

// HW sin/cos take revolutions; inputs a in [0,pi], delta in [-pi,pi] ->
// rev in [-0.5,0.5]: no range reduction needed.
#define INV_2PI 0.15915494309189535f
__device__ __forceinline__ float fsin(float a) {
#if __has_builtin(__builtin_amdgcn_sinf)
    return __builtin_amdgcn_sinf(a * INV_2PI);
#else
    return sinf(a);
#endif
}
__device__ __forceinline__ float fcos(float a) {
#if __has_builtin(__builtin_amdgcn_cosf)
    return __builtin_amdgcn_cosf(a * INV_2PI);
#else
    return cosf(a);
#endif
}

__device__ __forceinline__ float fclamp(float x, float lo, float hi) {
    return fminf(fmaxf(x, lo), hi);   // -> v_med3_f32
}

// One edge's contribution to the clamped Green integral
//   Area(P ∩ [-W,W]x[-H,H]) = ∮ clamp(x,-W,W) d(clamp(y,-H,H)).
// rx,ry are raw v_rcp of dx,dy — unguarded: for exactly-axis-parallel edges
// the ±inf propagates through min/max + clamp to the correct interval
// endpoints (outside-band edges collapse to zero contribution); NaN would
// need two simultaneous exact-zero coincidences (measure zero in this data).
// hdx = 0.5*dx (precomputed half-axis, reused across the edge pair).
__device__ __forceinline__ void edge_acc(float& acc, float px, float py,
                                         float dx, float dy, float hdx,
                                         float rx, float ry, float W, float H) {
    const float t0 = (-H - py) * ry;
    const float t1 = ( H - py) * ry;
    const float ta = fclamp(fminf(t0, t1), 0.0f, 1.0f);   // y-band entry
    const float tb = fclamp(fmaxf(t0, t1), 0.0f, 1.0f);   // y-band exit

    const float s0 = (-W - px) * rx;
    const float s1 = ( W - px) * rx;
    const float sa = fclamp(fminf(s0, s1), ta, tb);        // x-band entry
    const float sb = fclamp(fmaxf(s0, s1), ta, tb);        // x-band exit

    const float ya  = fmaf(ta, dy, py);
    const float ysa = fmaf(sa, dy, py);
    const float ysb = fmaf(sb, dy, py);
    const float yb  = fmaf(tb, dy, py);

    const float xac = fclamp(fmaf(ta, dx, px), -W, W);
    const float xbc = fclamp(fmaf(tb, dx, px), -W, W);
    const float xm  = fmaf(sa + sb, hdx, px);              // x(midpoint of [sa,sb])

    acc = fmaf(xac, ysa - ya,  acc);
    acc = fmaf(xm,  ysb - ysa, acc);
    acc = fmaf(xbc, yb  - ysb, acc);
}

__device__ __forceinline__ float iou_pair(float cx1, float cy1, float w1, float h1, float a1,
                                          float cx2, float cy2, float w2, float h2, float a2) {
    const float sA = fsin(a1), cA = fcos(a1);
    const float da = a2 - a1;
    const float sD = fsin(da), cD = fcos(da);   // relative rotation directly

    const float W = 0.5f * w1, H = 0.5f * h1;

    // box2 center in box1 frame.
    const float dxc = cx2 - cx1, dyc = cy2 - cy1;
    const float lx = fmaf(cA, dxc,  sA * dyc);
    const float ly = fmaf(cA, dyc, -sA * dxc);

    // Half-axes hu = 0.5*w2*(cD,sD), hv = 0.5*h2*(-sD,cD); full axes doubled.
    const float hw = 0.5f * w2, hh = 0.5f * h2;
    const float hux = hw * cD,  huy = hw * sD;
    const float hvx = -hh * sD, hvy = hh * cD;
    const float ux = hux + hux, uy = huy + huy;
    const float vx = hvx + hvx, vy = hvy + hvy;

    const float rux = frcp(ux), ruy = frcp(uy);
    const float rvx = frcp(vx), rvy = frcp(vy);

    // CCW corners l ± hu ± hv.
    const float c0x = lx + hux + hvx, c0y = ly + huy + hvy;
    const float c1x = lx - hux + hvx, c1y = ly - huy + hvy;
    const float c2x = lx - hux - hvx, c2y = ly - huy - hvy;
    const float c3x = lx + hux - hvx, c3y = ly + huy - hvy;

    float acc = 0.0f;
    edge_acc(acc, c0x, c0y, -ux, -uy, -hux, -rux, -ruy, W, H);
    edge_acc(acc, c1x, c1y, -vx, -vy, -hvx, -rvx, -rvy, W, H);
    edge_acc(acc, c2x, c2y,  ux,  uy,  hux,  rux,  ruy, W, H);
    edge_acc(acc, c3x, c3y,  vx,  vy,  hvx,  rvx,  rvy, W, H);

    const float inter = fabsf(acc);
    return inter * frcp(fmaf(w1, h1, w2 * h2) - inter);
}

// Two adjacent box pairs per thread: 10 dwordx2 loads + one float2 store.
__global__ __launch_bounds__(TPB, 8) void diff_iou_rotated_kernel(
    const float* __restrict__ box1, const float* __restrict__ box2,
    float* __restrict__ out, int n)
{
    const int t = blockIdx.x * TPB + threadIdx.x;
    const int i0 = 2 * t;
    if (i0 >= n) return;

    if (i0 + 1 < n) {
        const float2* p1 = (const float2*)(box1 + (size_t)i0 * 5);
        const float2* p2 = (const float2*)(box2 + (size_t)i0 * 5);
        const float2 A0 = p1[0], A1 = p1[1], A2 = p1[2], A3 = p1[3], A4 = p1[4];
        const float2 B0 = p2[0], B1 = p2[1], B2 = p2[2], B3 = p2[3], B4 = p2[4];

        const float r0 = iou_pair(A0.x, A0.y, A1.x, A1.y, A2.x,
                                  B0.x, B0.y, B1.x, B1.y, B2.x);
        const float r1 = iou_pair(A2.y, A3.x, A3.y, A4.x, A4.y,
                                  B2.y, B3.x, B3.y, B4.x, B4.y);
        *(float2*)(out + i0) = make_float2(r0, r1);
    } else {
        const float* p1 = box1 + (size_t)i0 * 5;
        const float* p2 = box2 + (size_t)i0 * 5;
        out[i0] = iou_pair(p1[0], p1[1], p1[2], p1[3], p1[4],
                           p2[0], p2[1], p2[2], p2[3], p2[4]);
    }
}

extern "C" void kernel_launch(void* const* d_in, const int* in_sizes, int n_in,
                              void* d_out, int out_size, void* d_ws, size_t ws_size,
                              hipStream_t stream) {
    const float* b1 = (const float*)d_in[0];
    const float* b2 = (const float*)d_in[1];
    float* out = (float*)d_out;
    const int n = in_sizes[0] / 5;   // (B,N,5) -> B*N pairs
    const int nthreads = (n + 1) / 2;
    const int blocks = (nthreads + TPB - 1) / TPB;
    hipLaunchKernelGGL(diff_iou_rotated_kernel, dim3(blocks), dim3(TPB), 0, stream,
                       b1, b2, out, n);
}